// Round 1
// 574.847 us; speedup vs baseline: 1.0878x; 1.0878x over previous
//
#include <hip/hip_runtime.h>
#include <hip/hip_bf16.h>

// Problem: B=4096, N=8192, D=1024
//   h = x*mask/0.75
//   enc = tanh(h @ W^T + b1)          GEMM1: [B,N]x[D,N]^T -> [B,D]  (split-K=4)
//   final = LN_D(enc)*gamma + beta    (output 0, B*D f32)
//   recon = enc @ W + b2              GEMM2: [B,D]x[D,N] -> [B,N] (not materialized)
//   loss = sum_b sum_n (nz*(x-recon))^2 / sum_n nz    (output 1, 1 f32)
//
// R1: double-buffered LDS prefetch (T3-minimum 2-phase) on both GEMMs;
//     gemm2 epilogue x staged via LDS (half overlapped with last K-iter).

#define Bdim 4096
#define Ndim 8192
#define Ddim 1024
#define SPLITK 4
#define KC (Ndim / SPLITK)   // 2048

typedef short short8 __attribute__((ext_vector_type(8)));
typedef float floatx4 __attribute__((ext_vector_type(4)));

__device__ __forceinline__ ushort f2bf(float f) {
    union { float f; unsigned int u; } v; v.f = f;
    unsigned int r = (v.u + 0x7FFFu + ((v.u >> 16) & 1u)) >> 16;
    return (ushort)r;
}
__device__ __forceinline__ float bf2f(ushort u) {
    union { unsigned int u; float f; } v; v.u = ((unsigned int)u) << 16;
    return v.f;
}
__device__ __forceinline__ unsigned int pk(ushort a, ushort b) {
    return (unsigned int)a | ((unsigned int)b << 16);
}

// async global->LDS, 16B per lane. LDS dest is wave-uniform base + lane*16.
__device__ __forceinline__ void gl_lds16(const void* g, void* l) {
    __builtin_amdgcn_global_load_lds(
        (const __attribute__((address_space(1))) unsigned int*)g,
        (__attribute__((address_space(3))) unsigned int*)l,
        16, 0, 0);
}

// stage one 128x64 bf16 A-tile + 128x64 bf16 B-tile into dst (32 KB),
// XOR-pre-swizzled source so the swizzled frag reads see linear LDS (rule 21).
__device__ __forceinline__ void stage_ab(const ushort* __restrict__ gA,
                                         const ushort* __restrict__ gB,
                                         long ldg, ushort* dst, int t) {
    int wofs = (t & 192) * 8;  // wave-uniform chunk base (ushorts)
    #pragma unroll
    for (int p = 0; p < 4; p++) {
        int c = p * 256 + t;
        int r = c >> 3, cc = c & 7;
        int g = cc ^ (r & 7);
        gl_lds16(gA + (size_t)r * ldg + g * 8, dst + p * 2048 + wofs);
    }
    #pragma unroll
    for (int p = 0; p < 4; p++) {
        int c = p * 256 + t;
        int r = c >> 3, cc = c & 7;
        int g = cc ^ (r & 7);
        gl_lds16(gB + (size_t)r * ldg + g * 8, dst + 8192 + p * 2048 + wofs);
    }
}

// stage 64 rows x 128 f32 of x (32 KB) linearly into dst
__device__ __forceinline__ void stage_x(const float* __restrict__ gx, long ldx,
                                        ushort* dst, int t) {
    int wofs = (t & 192) * 8;
    #pragma unroll
    for (int p = 0; p < 8; p++) {
        int c = p * 256 + t;
        int r = c >> 5, cc = c & 31;
        gl_lds16(gx + (size_t)r * ldx + cc * 4, dst + p * 2048 + wofs);
    }
}

// ---------------- prep: h = bf16(x*mask/0.75) ----------------
__global__ void prep_h_kernel(const float* __restrict__ x, const float* __restrict__ mask,
                              ushort* __restrict__ h) {
    const float C = 1.0f / 0.75f;
    size_t i = ((size_t)blockIdx.x * 256 + threadIdx.x) * 8;
    float4 x0 = *(const float4*)&x[i];
    float4 x1 = *(const float4*)&x[i + 4];
    float4 m0 = *(const float4*)&mask[i];
    float4 m1 = *(const float4*)&mask[i + 4];
    uint4 o;
    o.x = pk(f2bf(x0.x * m0.x * C), f2bf(x0.y * m0.y * C));
    o.y = pk(f2bf(x0.z * m0.z * C), f2bf(x0.w * m0.w * C));
    o.z = pk(f2bf(x1.x * m1.x * C), f2bf(x1.y * m1.y * C));
    o.w = pk(f2bf(x1.z * m1.z * C), f2bf(x1.w * m1.w * C));
    *(uint4*)&h[i] = o;
}

// ---------------- prep: Wb = bf16(W), Wt = bf16(W^T) ----------------
__global__ void prep_w_kernel(const float* __restrict__ W, ushort* __restrict__ Wb,
                              ushort* __restrict__ Wt) {
    __shared__ float tl[64][65];
    int n0 = blockIdx.x * 64, d0 = blockIdx.y * 64;
    int tx = threadIdx.x, ty = threadIdx.y;  // 64 x 4
    for (int i = ty; i < 64; i += 4) {
        float v = W[(size_t)(d0 + i) * Ndim + n0 + tx];
        tl[i][tx] = v;
        Wb[(size_t)(d0 + i) * Ndim + n0 + tx] = f2bf(v);
    }
    __syncthreads();
    for (int i = ty; i < 64; i += 4)
        Wt[(size_t)(n0 + i) * Ddim + d0 + tx] = f2bf(tl[tx][i]);
}

// ---------------- GEMM1 split-K: part[kc] = h_chunk @ W_chunk^T ----------------
// BM=128, BN=128, BK=64, K-chunk 2048. 4 waves 2x2; wave tile 64x64.
// Double-buffered LDS prefetch: one barrier per K-step.
__global__ void __launch_bounds__(256) gemm1_sk_kernel(
        const ushort* __restrict__ A,    // h bf16 [B][N]
        const ushort* __restrict__ Wb,   // [D][N] bf16
        float* __restrict__ part) {      // [SPLITK][B][D] f32
    const int K = Ndim;
    // flat LDS: buffer b occupies [b*16384, b*16384+16384) ushorts (A at +0, B at +8192)
    __shared__ __attribute__((aligned(16))) ushort S[2 * 16384];  // 64 KB
    int n0 = blockIdx.x * 128, m0 = blockIdx.y * 128;
    int kb0 = blockIdx.z * KC;
    int t = threadIdx.x;
    int lane = t & 63, w = t >> 6;
    int wm = w >> 1, wn = w & 1;
    int quad = lane >> 4, lrow = lane & 15;

    const ushort* gA = &A[(size_t)m0 * K];
    const ushort* gB = &Wb[(size_t)n0 * K];

    floatx4 acc[4][4];
    for (int i = 0; i < 4; i++) for (int j = 0; j < 4; j++) acc[i][j] = (floatx4)0.0f;

    stage_ab(gA + kb0, gB + kb0, K, S, t);
    __syncthreads();
    int cur = 0;
    for (int k0 = kb0; k0 < kb0 + KC; k0 += 64) {
        // prefetch next tile into the other buffer (stays in flight during MFMA)
        if (k0 + 64 < kb0 + KC)
            stage_ab(gA + k0 + 64, gB + k0 + 64, K, S + (cur ^ 1) * 16384, t);
        const ushort* As = S + cur * 16384;
        const ushort* Bs = As + 8192;
        short8 af[2][4], bfr[2][4];
        #pragma unroll
        for (int k1 = 0; k1 < 2; k1++) {
            #pragma unroll
            for (int i = 0; i < 4; i++) {
                int r = wm * 64 + i * 16 + lrow;
                int q = (k1 * 4 + quad) ^ (r & 7);
                af[k1][i] = *(const short8*)&As[r * 64 + q * 8];
            }
            #pragma unroll
            for (int j = 0; j < 4; j++) {
                int r = wn * 64 + j * 16 + lrow;
                int q = (k1 * 4 + quad) ^ (r & 7);
                bfr[k1][j] = *(const short8*)&Bs[r * 64 + q * 8];
            }
        }
        #pragma unroll
        for (int k1 = 0; k1 < 2; k1++)
            #pragma unroll
            for (int i = 0; i < 4; i++)
                #pragma unroll
                for (int j = 0; j < 4; j++)
                    acc[i][j] = __builtin_amdgcn_mfma_f32_16x16x32_bf16(af[k1][i], bfr[k1][j], acc[i][j], 0, 0, 0);
        __syncthreads();  // drains vmcnt (prefetch done) + lgkm; protects buffer reuse
        cur ^= 1;
    }
    // epilogue: write f32 partials
    float* pb = &part[(size_t)blockIdx.z * Bdim * Ddim];
    for (int i = 0; i < 4; i++) {
        for (int r = 0; r < 4; r++) {
            int row = m0 + wm * 64 + i * 16 + quad * 4 + r;
            for (int j = 0; j < 4; j++) {
                int col = n0 + wn * 64 + j * 16 + lrow;
                pb[(size_t)row * Ddim + col] = acc[i][j][r];
            }
        }
    }
}

// ---------------- reduce partials + b1 + tanh -> enc; fused LayerNorm -> final ----------------
__global__ void reduce_ln_kernel(const float* __restrict__ part, const float* __restrict__ b1,
                                 const float* __restrict__ gamma, const float* __restrict__ beta,
                                 ushort* __restrict__ enc, float* __restrict__ out) {
    int row = blockIdx.x;
    int t = threadIdx.x;  // 256 threads, 4 elems each
    size_t base = (size_t)row * Ddim + t * 4;
    float4 v = *(const float4*)&part[base];
    #pragma unroll
    for (int kc = 1; kc < SPLITK; kc++) {
        float4 p = *(const float4*)&part[(size_t)kc * Bdim * Ddim + base];
        v.x += p.x; v.y += p.y; v.z += p.z; v.w += p.w;
    }
    float4 bb = *(const float4*)&b1[t * 4];
    float v0 = tanhf(v.x + bb.x), v1 = tanhf(v.y + bb.y);
    float v2 = tanhf(v.z + bb.z), v3 = tanhf(v.w + bb.w);
    // store enc as bf16 (input to GEMM2)
    uint2 eo;
    eo.x = pk(f2bf(v0), f2bf(v1));
    eo.y = pk(f2bf(v2), f2bf(v3));
    *(uint2*)&enc[base] = eo;
    // layernorm over D=1024
    float s = v0 + v1 + v2 + v3;
    float sq = v0 * v0 + v1 * v1 + v2 * v2 + v3 * v3;
    for (int sft = 1; sft < 64; sft <<= 1) {
        s += __shfl_xor(s, sft);
        sq += __shfl_xor(sq, sft);
    }
    __shared__ float red[8];
    int w = t >> 6, lane = t & 63;
    if (lane == 0) { red[w] = s; red[w + 4] = sq; }
    __syncthreads();
    s = red[0] + red[1] + red[2] + red[3];
    sq = red[4] + red[5] + red[6] + red[7];
    float mu = s * (1.0f / Ddim);
    float var = sq * (1.0f / Ddim) - mu * mu;
    float rstd = rsqrtf(var + 1e-5f);
    float4 g = *(const float4*)&gamma[t * 4];
    float4 b = *(const float4*)&beta[t * 4];
    float4 o;
    o.x = (v0 - mu) * rstd * g.x + b.x;
    o.y = (v1 - mu) * rstd * g.y + b.y;
    o.z = (v2 - mu) * rstd * g.z + b.z;
    o.w = (v3 - mu) * rstd * g.w + b.w;
    *(float4*)&out[base] = o;
}

// ---------------- GEMM1 fallback (no split-K ws): BM=128,BN=64,BK=64 ----------------
__global__ void __launch_bounds__(256) gemm1_kernel(
        const ushort* __restrict__ A, const ushort* __restrict__ Wb,
        const float* __restrict__ b1, ushort* __restrict__ enc) {
    const int K = Ndim;
    __shared__ __attribute__((aligned(16))) ushort As[128][64];
    __shared__ __attribute__((aligned(16))) ushort Bs[64][64];
    int m0 = blockIdx.y * 128, n0 = blockIdx.x * 64;
    int t = threadIdx.x;
    int lane = t & 63, w = t >> 6;
    int wm = w >> 1, wn = w & 1;
    int quad = lane >> 4, lrow = lane & 15;
    ushort* AsF = &As[0][0];
    ushort* BsF = &Bs[0][0];
    int wofs = (t & 192) * 8;

    floatx4 acc[4][2];
    for (int i = 0; i < 4; i++) for (int j = 0; j < 2; j++) acc[i][j] = (floatx4)0.0f;

    for (int k0 = 0; k0 < K; k0 += 64) {
        #pragma unroll
        for (int p = 0; p < 4; p++) {
            int c = p * 256 + t;
            int r = c >> 3, cc = c & 7;
            int g = cc ^ (r & 7);
            gl_lds16(&A[(size_t)(m0 + r) * K + k0 + g * 8], AsF + p * 2048 + wofs);
        }
        #pragma unroll
        for (int p = 0; p < 2; p++) {
            int c = p * 256 + t;
            int r = c >> 3, cc = c & 7;
            int g = cc ^ (r & 7);
            gl_lds16(&Wb[(size_t)(n0 + r) * K + k0 + g * 8], BsF + p * 2048 + wofs);
        }
        __syncthreads();
        short8 af[2][4], bfr[2][2];
        #pragma unroll
        for (int k1 = 0; k1 < 2; k1++) {
            #pragma unroll
            for (int i = 0; i < 4; i++) {
                int r = wm * 64 + i * 16 + lrow;
                int q = (k1 * 4 + quad) ^ (r & 7);
                af[k1][i] = *(const short8*)&As[r][q * 8];
            }
            #pragma unroll
            for (int j = 0; j < 2; j++) {
                int r = wn * 32 + j * 16 + lrow;
                int q = (k1 * 4 + quad) ^ (r & 7);
                bfr[k1][j] = *(const short8*)&Bs[r][q * 8];
            }
        }
        #pragma unroll
        for (int k1 = 0; k1 < 2; k1++)
            #pragma unroll
            for (int i = 0; i < 4; i++)
                #pragma unroll
                for (int j = 0; j < 2; j++)
                    acc[i][j] = __builtin_amdgcn_mfma_f32_16x16x32_bf16(af[k1][i], bfr[k1][j], acc[i][j], 0, 0, 0);
        __syncthreads();
    }
    for (int j = 0; j < 2; j++) {
        int col = n0 + wn * 32 + j * 16 + lrow;
        float bb = b1[col];
        for (int i = 0; i < 4; i++) {
            for (int r = 0; r < 4; r++) {
                int row = m0 + wm * 64 + i * 16 + quad * 4 + r;
                float v = tanhf(acc[i][j][r] + bb);
                enc[(size_t)row * Ddim + col] = f2bf(v);
            }
        }
    }
}

// ---------------- GEMM1 fallback (ws too small): convert x*mask in-staging ----------------
__global__ void gemm1_conv_kernel(const float* __restrict__ x, const float* __restrict__ mask,
                                  const ushort* __restrict__ Wb, const float* __restrict__ b1,
                                  ushort* __restrict__ enc) {
    const int K = Ndim;
    __shared__ __attribute__((aligned(16))) ushort As[128][32];
    __shared__ __attribute__((aligned(16))) ushort Bs[64][32];
    int m0 = blockIdx.y * 128, n0 = blockIdx.x * 64;
    int t = threadIdx.x;
    int lane = t & 63, w = t >> 6;
    int wm = w >> 1, wn = w & 1;
    int quad = lane >> 4, lrow = lane & 15;
    const float C = 1.0f / 0.75f;

    floatx4 acc[4][2];
    for (int i = 0; i < 4; i++) for (int j = 0; j < 2; j++) acc[i][j] = (floatx4)0.0f;

    for (int k0 = 0; k0 < K; k0 += 32) {
        for (int c = t; c < 512; c += 256) {
            int r = c >> 2, cc = (c & 3) * 8;
            const float* px = &x[(size_t)(m0 + r) * K + k0 + cc];
            const float* pm = &mask[(size_t)(m0 + r) * K + k0 + cc];
            float4 xa = *(const float4*)px, xb = *(const float4*)(px + 4);
            float4 ma = *(const float4*)pm, mb = *(const float4*)(pm + 4);
            uint4 o;
            o.x = pk(f2bf(xa.x * ma.x * C), f2bf(xa.y * ma.y * C));
            o.y = pk(f2bf(xa.z * ma.z * C), f2bf(xa.w * ma.w * C));
            o.z = pk(f2bf(xb.x * mb.x * C), f2bf(xb.y * mb.y * C));
            o.w = pk(f2bf(xb.z * mb.z * C), f2bf(xb.w * mb.w * C));
            *(uint4*)&As[r][cc] = o;
        }
        {
            int c = t;
            int r = c >> 2, cc = (c & 3) * 8;
            *(uint4*)&Bs[r][cc] = *(const uint4*)&Wb[(size_t)(n0 + r) * K + k0 + cc];
        }
        __syncthreads();
        short8 af[4], bfr[2];
        for (int i = 0; i < 4; i++) af[i] = *(const short8*)&As[wm * 64 + i * 16 + lrow][quad * 8];
        for (int j = 0; j < 2; j++) bfr[j] = *(const short8*)&Bs[wn * 32 + j * 16 + lrow][quad * 8];
        for (int i = 0; i < 4; i++)
            for (int j = 0; j < 2; j++)
                acc[i][j] = __builtin_amdgcn_mfma_f32_16x16x32_bf16(af[i], bfr[j], acc[i][j], 0, 0, 0);
        __syncthreads();
    }
    for (int j = 0; j < 2; j++) {
        int col = n0 + wn * 32 + j * 16 + lrow;
        float bb = b1[col];
        for (int i = 0; i < 4; i++) {
            for (int r = 0; r < 4; r++) {
                int row = m0 + wm * 64 + i * 16 + quad * 4 + r;
                float v = tanhf(acc[i][j][r] + bb);
                enc[(size_t)row * Ddim + col] = f2bf(v);
            }
        }
    }
}

// ---------------- GEMM2: recon loss partials ----------------
// BM=128, BN=128, BK=64, K=1024 (16 iters). Double-buffered prefetch;
// x-tile (128x128 f32, 64 KB) staged via LDS: half 0 overlapped with last K-iter.
__global__ void __launch_bounds__(256) gemm2_kernel(
        const ushort* __restrict__ enc,  // [B][D] bf16
        const ushort* __restrict__ Wt,   // [N][D] bf16
        const float* __restrict__ b2,
        const float* __restrict__ x,     // [B][N] f32
        float* __restrict__ num, float* __restrict__ den) {
    const int K = Ddim;
    __shared__ __attribute__((aligned(16))) ushort S[2 * 16384];  // 64 KB
    int m0 = blockIdx.y * 128, n0 = blockIdx.x * 128;
    int t = threadIdx.x;
    int lane = t & 63, w = t >> 6;
    int wm = w >> 1, wn = w & 1;
    int quad = lane >> 4, lrow = lane & 15;

    const ushort* gA = &enc[(size_t)m0 * K];
    const ushort* gB = &Wt[(size_t)n0 * K];

    floatx4 acc[4][4];
    for (int i = 0; i < 4; i++) for (int j = 0; j < 4; j++) acc[i][j] = (floatx4)0.0f;

    stage_ab(gA, gB, K, S, t);
    __syncthreads();
    int cur = 0;
    for (int k0 = 0; k0 < K; k0 += 64) {
        if (k0 + 64 < K) {
            stage_ab(gA + k0 + 64, gB + k0 + 64, K, S + (cur ^ 1) * 16384, t);
        } else {
            // last iter (cur==1): buffer 0 is free -> stage x rows 0..63 (32 KB)
            // so half the x fetch hides under the final MFMAs.
            stage_x(&x[(size_t)m0 * Ndim + n0], Ndim, S, t);
        }
        const ushort* As = S + cur * 16384;
        const ushort* Bs = As + 8192;
        short8 af[2][4], bfr[2][4];
        #pragma unroll
        for (int k1 = 0; k1 < 2; k1++) {
            #pragma unroll
            for (int i = 0; i < 4; i++) {
                int r = wm * 64 + i * 16 + lrow;
                int q = (k1 * 4 + quad) ^ (r & 7);
                af[k1][i] = *(const short8*)&As[r * 64 + q * 8];
            }
            #pragma unroll
            for (int j = 0; j < 4; j++) {
                int r = wn * 64 + j * 16 + lrow;
                int q = (k1 * 4 + quad) ^ (r & 7);
                bfr[k1][j] = *(const short8*)&Bs[r * 64 + q * 8];
            }
        }
        #pragma unroll
        for (int k1 = 0; k1 < 2; k1++)
            #pragma unroll
            for (int i = 0; i < 4; i++)
                #pragma unroll
                for (int j = 0; j < 4; j++)
                    acc[i][j] = __builtin_amdgcn_mfma_f32_16x16x32_bf16(af[k1][i], bfr[k1][j], acc[i][j], 0, 0, 0);
        __syncthreads();
        cur ^= 1;
    }
    // buffer 1 now free -> stage x rows 64..127
    stage_x(&x[(size_t)(m0 + 64) * Ndim + n0], Ndim, S + 16384, t);
    __syncthreads();

    const float* xs = (const float*)S;  // half h at float offset h*8192, row-major [64][128]
    // hoist b2 (4 distinct cols per thread)
    float b2v[4];
    #pragma unroll
    for (int j = 0; j < 4; j++) b2v[j] = b2[n0 + wn * 64 + j * 16 + lrow];

    // epilogue: per-row sum of (x - (acc+b2))^2
    for (int i = 0; i < 4; i++) {
        for (int r = 0; r < 4; r++) {
            int rl = wm * 64 + i * 16 + quad * 4 + r;
            int row = m0 + rl;
            float ns = 0.0f, ds = 0.0f;
            #pragma unroll
            for (int j = 0; j < 4; j++) {
                int cl = wn * 64 + j * 16 + lrow;
                float recon = acc[i][j][r] + b2v[j];
                float xv = xs[wm * 8192 + (rl & 63) * 128 + cl];
                if (xv != 0.0f) {
                    float d = xv - recon;
                    ns += d * d;
                    ds += 1.0f;
                }
            }
            for (int s = 1; s < 16; s <<= 1) {
                ns += __shfl_xor(ns, s);
                ds += __shfl_xor(ds, s);
            }
            if (lrow == 0) {
                atomicAdd(&num[row], ns);
                atomicAdd(&den[row], ds);
            }
        }
    }
}

// ---------------- LayerNorm over D (fallback path) ----------------
__global__ void ln_kernel(const ushort* __restrict__ enc, const float* __restrict__ gamma,
                          const float* __restrict__ beta, float* __restrict__ out) {
    int row = blockIdx.x;
    int t = threadIdx.x;
    const ushort* e = &enc[(size_t)row * Ddim];
    uint2 u = *(const uint2*)&e[t * 4];
    float v0 = bf2f((ushort)(u.x & 0xFFFF)), v1 = bf2f((ushort)(u.x >> 16));
    float v2 = bf2f((ushort)(u.y & 0xFFFF)), v3 = bf2f((ushort)(u.y >> 16));
    float s = v0 + v1 + v2 + v3;
    float sq = v0 * v0 + v1 * v1 + v2 * v2 + v3 * v3;
    for (int sft = 1; sft < 64; sft <<= 1) {
        s += __shfl_xor(s, sft);
        sq += __shfl_xor(sq, sft);
    }
    __shared__ float red[8];
    int w = t >> 6, lane = t & 63;
    if (lane == 0) { red[w] = s; red[w + 4] = sq; }
    __syncthreads();
    s = red[0] + red[1] + red[2] + red[3];
    sq = red[4] + red[5] + red[6] + red[7];
    float mu = s * (1.0f / Ddim);
    float var = sq * (1.0f / Ddim) - mu * mu;
    float rstd = rsqrtf(var + 1e-5f);
    float4 g = *(const float4*)&gamma[t * 4];
    float4 b = *(const float4*)&beta[t * 4];
    float4 o;
    o.x = (v0 - mu) * rstd * g.x + b.x;
    o.y = (v1 - mu) * rstd * g.y + b.y;
    o.z = (v2 - mu) * rstd * g.z + b.z;
    o.w = (v3 - mu) * rstd * g.w + b.w;
    *(float4*)&out[(size_t)row * Ddim + t * 4] = o;
}

// ---------------- loss = sum_b num[b]/den[b] ----------------
__global__ void loss_final_kernel(const float* __restrict__ num, const float* __restrict__ den,
                                  float* __restrict__ out) {
    int t = threadIdx.x;
    float s = 0.0f;
    for (int i = t; i < Bdim; i += 256) s += num[i] / den[i];
    for (int sft = 1; sft < 64; sft <<= 1) s += __shfl_xor(s, sft);
    __shared__ float red[4];
    int w = t >> 6, lane = t & 63;
    if (lane == 0) red[w] = s;
    __syncthreads();
    if (t == 0) out[0] = red[0] + red[1] + red[2] + red[3];
}

// ---------------- workspace layout ----------------
#define WB_OFF   0ull
#define WB_SZ    ((size_t)Ddim * Ndim * 2)            // 16 MiB
#define WT_OFF   (WB_OFF + WB_SZ)
#define WT_SZ    ((size_t)Ndim * Ddim * 2)            // 16 MiB
#define ENC_OFF  (WT_OFF + WT_SZ)
#define ENC_SZ   ((size_t)Bdim * Ddim * 2)            // 8 MiB
#define NUM_OFF  (ENC_OFF + ENC_SZ)
#define NUM_SZ   ((size_t)Bdim * 4)
#define DEN_OFF  (NUM_OFF + NUM_SZ)
#define DEN_SZ   ((size_t)Bdim * 4)
#define H_OFF    (DEN_OFF + DEN_SZ)
#define H_SZ     ((size_t)Bdim * Ndim * 2)            // 64 MiB
#define FAST_NEED (H_OFF + H_SZ)
#define PART_OFF FAST_NEED
#define PART_SZ  ((size_t)SPLITK * Bdim * Ddim * 4)   // 64 MiB
#define SPLIT_NEED (PART_OFF + PART_SZ)

extern "C" void kernel_launch(void* const* d_in, const int* in_sizes, int n_in,
                              void* d_out, int out_size, void* d_ws, size_t ws_size,
                              hipStream_t stream) {
    const float* x     = (const float*)d_in[0];
    const float* mask  = (const float*)d_in[1];
    const float* W     = (const float*)d_in[2];
    const float* b1    = (const float*)d_in[3];
    const float* b2    = (const float*)d_in[4];
    const float* gamma = (const float*)d_in[5];
    const float* beta  = (const float*)d_in[6];

    float* final_out = (float*)d_out;                       // [B*D]
    float* loss_out  = final_out + (size_t)Bdim * Ddim;     // [1]

    char* ws = (char*)d_ws;
    ushort* Wb   = (ushort*)(ws + WB_OFF);
    ushort* Wt   = (ushort*)(ws + WT_OFF);
    ushort* enc  = (ushort*)(ws + ENC_OFF);
    float*  num  = (float*)(ws + NUM_OFF);
    float*  den  = (float*)(ws + DEN_OFF);
    ushort* hbuf = (ushort*)(ws + H_OFF);
    float*  part = (float*)(ws + PART_OFF);

    hipMemsetAsync(num, 0, NUM_SZ + DEN_SZ, stream);

    prep_w_kernel<<<dim3(Ndim / 64, Ddim / 64), dim3(64, 4), 0, stream>>>(W, Wb, Wt);

    if (ws_size >= SPLIT_NEED) {
        prep_h_kernel<<<(Bdim * (size_t)Ndim) / 8 / 256, 256, 0, stream>>>(x, mask, hbuf);
        gemm1_sk_kernel<<<dim3(Ddim / 128, Bdim / 128, SPLITK), 256, 0, stream>>>(hbuf, Wb, part);
        reduce_ln_kernel<<<Bdim, 256, 0, stream>>>(part, b1, gamma, beta, enc, final_out);
    } else if (ws_size >= FAST_NEED) {
        prep_h_kernel<<<(Bdim * (size_t)Ndim) / 8 / 256, 256, 0, stream>>>(x, mask, hbuf);
        gemm1_kernel<<<dim3(Ddim / 64, Bdim / 128), 256, 0, stream>>>(hbuf, Wb, b1, enc);
        ln_kernel<<<Bdim, 256, 0, stream>>>(enc, gamma, beta, final_out);
    } else {
        gemm1_conv_kernel<<<dim3(Ddim / 64, Bdim / 128), 256, 0, stream>>>(x, mask, Wb, b1, enc);
        ln_kernel<<<Bdim, 256, 0, stream>>>(enc, gamma, beta, final_out);
    }

    gemm2_kernel<<<dim3(Ndim / 128, Bdim / 128), 256, 0, stream>>>(enc, Wt, b2, x, num, den);

    loss_final_kernel<<<1, 256, 0, stream>>>(num, den, loss_out);
}

// Round 2
// 541.725 us; speedup vs baseline: 1.1544x; 1.0611x over previous
//
#include <hip/hip_runtime.h>
#include <hip/hip_bf16.h>

// Problem: B=4096, N=8192, D=1024
//   h = x*mask/0.75
//   enc = tanh(h @ W^T + b1)          GEMM1: [B,N]x[D,N]^T -> [B,D]  (split-K=4)
//   final = LN_D(enc)*gamma + beta    (output 0, B*D f32)
//   recon = enc @ W + b2              GEMM2: [B,D]x[D,N] -> [B,N] (not materialized)
//   loss = sum_b sum_n (nz*(x-recon))^2 / sum_n nz    (output 1, 1 f32)
//
// R2: both GEMMs -> 256x256 tile, BK=32, 8 waves (2Mx4N), 3-buffer LDS rotation
//     (96 KB), 2 phases/tile, counted vmcnt(4) at tile boundaries (never 0 in
//     main loop), raw s_barrier + lgkmcnt(0)+sched_barrier + setprio (T3/T4/T5).

#define Bdim 4096
#define Ndim 8192
#define Ddim 1024
#define SPLITK 4
#define KC (Ndim / SPLITK)   // 2048

typedef short short8 __attribute__((ext_vector_type(8)));
typedef float floatx4 __attribute__((ext_vector_type(4)));

__device__ __forceinline__ ushort f2bf(float f) {
    union { float f; unsigned int u; } v; v.f = f;
    unsigned int r = (v.u + 0x7FFFu + ((v.u >> 16) & 1u)) >> 16;
    return (ushort)r;
}
__device__ __forceinline__ float bf2f(ushort u) {
    union { unsigned int u; float f; } v; v.u = ((unsigned int)u) << 16;
    return v.f;
}
__device__ __forceinline__ unsigned int pk(ushort a, ushort b) {
    return (unsigned int)a | ((unsigned int)b << 16);
}

// async global->LDS, 16B per lane. LDS dest is wave-uniform base + lane*16.
__device__ __forceinline__ void gl_lds16(const void* g, void* l) {
    __builtin_amdgcn_global_load_lds(
        (const __attribute__((address_space(1))) unsigned int*)g,
        (__attribute__((address_space(3))) unsigned int*)l,
        16, 0, 0);
}

// Stage one 256x32 bf16 operand tile (16 KB) into LDS.
// 1024 chunks of 16B; 512 threads x 2 loads. Row = 4 chunks; source chunk is
// XOR-swizzled with ((r>>1)&3) so b128 frag reads are 2-way (free) on banks.
__device__ __forceinline__ void stage_op32(const ushort* __restrict__ g, long ldg,
                                           ushort* dst, int t) {
    int wofs = (t & 448) * 8;  // wave-uniform chunk base (ushorts)
    #pragma unroll
    for (int p = 0; p < 2; p++) {
        int c = p * 512 + t;
        int r = c >> 2, cc = c & 3;
        int gc = cc ^ ((r >> 1) & 3);
        gl_lds16(g + (size_t)r * ldg + gc * 8, dst + p * 4096 + wofs);
    }
}

// ---------------- prep: h = bf16(x*mask/0.75) ----------------
__global__ void prep_h_kernel(const float* __restrict__ x, const float* __restrict__ mask,
                              ushort* __restrict__ h) {
    const float C = 1.0f / 0.75f;
    size_t i = ((size_t)blockIdx.x * 256 + threadIdx.x) * 8;
    float4 x0 = *(const float4*)&x[i];
    float4 x1 = *(const float4*)&x[i + 4];
    float4 m0 = *(const float4*)&mask[i];
    float4 m1 = *(const float4*)&mask[i + 4];
    uint4 o;
    o.x = pk(f2bf(x0.x * m0.x * C), f2bf(x0.y * m0.y * C));
    o.y = pk(f2bf(x0.z * m0.z * C), f2bf(x0.w * m0.w * C));
    o.z = pk(f2bf(x1.x * m1.x * C), f2bf(x1.y * m1.y * C));
    o.w = pk(f2bf(x1.z * m1.z * C), f2bf(x1.w * m1.w * C));
    *(uint4*)&h[i] = o;
}

// ---------------- prep: Wb = bf16(W), Wt = bf16(W^T) ----------------
__global__ void prep_w_kernel(const float* __restrict__ W, ushort* __restrict__ Wb,
                              ushort* __restrict__ Wt) {
    __shared__ float tl[64][65];
    int n0 = blockIdx.x * 64, d0 = blockIdx.y * 64;
    int tx = threadIdx.x, ty = threadIdx.y;  // 64 x 4
    for (int i = ty; i < 64; i += 4) {
        float v = W[(size_t)(d0 + i) * Ndim + n0 + tx];
        tl[i][tx] = v;
        Wb[(size_t)(d0 + i) * Ndim + n0 + tx] = f2bf(v);
    }
    __syncthreads();
    for (int i = ty; i < 64; i += 4)
        Wt[(size_t)(n0 + i) * Ddim + d0 + tx] = f2bf(tl[tx][i]);
}

// ======================= 256x256 BK=32 pipelined GEMM core =======================
// 512 threads = 8 waves, wave grid 2(M) x 4(N); per-wave output 128x64.
// LDS buffer = 16 KB A (256x32) + 16 KB B (256x32) = 32 KB; 3 buffers rotate.
// Tile t reads buf[t%3]; tile t+2 stages into buf[(t+2)%3]; vmcnt(4) at tile end
// guarantees tile t+1 landed while t+2's 4 loads stay in flight.
// Phase mh (0/1): 16 MFMA = A m-frags [mh*4,mh*4+4) x 4 B n-frags, K=32.

#define GEMM_CORE_LOOP(NT_, gA_, gB_, ldg_)                                          \
    ushort* buf0 = S;                                                                \
    ushort* buf1 = S + 16384;                                                        \
    ushort* buf2 = S + 32768;                                                        \
    stage_op32(gA_, ldg_, buf0, t);                                                  \
    stage_op32(gB_, ldg_, buf0 + 8192, t);                                           \
    stage_op32(gA_ + 32, ldg_, buf1, t);                                             \
    stage_op32(gB_ + 32, ldg_, buf1 + 8192, t);                                      \
    asm volatile("s_waitcnt vmcnt(4)" ::: "memory");                                 \
    __builtin_amdgcn_s_barrier();                                                    \
    _Pragma("unroll 1")                                                              \
    for (int tt = 0; tt < NT_; ++tt) {                                               \
        const ushort* Ab = buf0 + wm * 4096 + pchunk;                                \
        const ushort* Bb = buf0 + 8192 + wn * 2048 + pchunk;                         \
        short8 afr[4], bfr[4];                                                       \
        /* ---- phase 0 (mh=0) ---- */                                               \
        _Pragma("unroll")                                                            \
        for (int j = 0; j < 4; j++) bfr[j] = *(const short8*)(Bb + j * 512);         \
        _Pragma("unroll")                                                            \
        for (int i = 0; i < 4; i++) afr[i] = *(const short8*)(Ab + i * 512);         \
        if (tt + 2 < NT_)                                                            \
            stage_op32(gA_ + (size_t)(tt + 2) * 32, ldg_, buf2, t);                  \
        __builtin_amdgcn_s_barrier();                                                \
        asm volatile("s_waitcnt lgkmcnt(0)" ::: "memory");                           \
        __builtin_amdgcn_sched_barrier(0);                                           \
        __builtin_amdgcn_s_setprio(1);                                               \
        _Pragma("unroll")                                                            \
        for (int i = 0; i < 4; i++)                                                  \
            _Pragma("unroll")                                                        \
            for (int j = 0; j < 4; j++)                                              \
                acc[i][j] = __builtin_amdgcn_mfma_f32_16x16x32_bf16(                 \
                    afr[i], bfr[j], acc[i][j], 0, 0, 0);                             \
        __builtin_amdgcn_s_setprio(0);                                               \
        __builtin_amdgcn_s_barrier();                                                \
        /* ---- phase 1 (mh=1) ---- */                                               \
        _Pragma("unroll")                                                            \
        for (int i = 0; i < 4; i++) afr[i] = *(const short8*)(Ab + 2048 + i * 512);  \
        if (tt + 2 < NT_)                                                            \
            stage_op32(gB_ + (size_t)(tt + 2) * 32, ldg_, buf2 + 8192, t);           \
        __builtin_amdgcn_s_barrier();                                                \
        asm volatile("s_waitcnt lgkmcnt(0)" ::: "memory");                           \
        __builtin_amdgcn_sched_barrier(0);                                           \
        __builtin_amdgcn_s_setprio(1);                                               \
        _Pragma("unroll")                                                            \
        for (int i = 0; i < 4; i++)                                                  \
            _Pragma("unroll")                                                        \
            for (int j = 0; j < 4; j++)                                              \
                acc[4 + i][j] = __builtin_amdgcn_mfma_f32_16x16x32_bf16(             \
                    afr[i], bfr[j], acc[4 + i][j], 0, 0, 0);                         \
        __builtin_amdgcn_s_setprio(0);                                               \
        if (tt + 2 < NT_) {                                                          \
            asm volatile("s_waitcnt vmcnt(4)" ::: "memory");                         \
        } else if (tt + 2 == NT_) {                                                  \
            asm volatile("s_waitcnt vmcnt(0)" ::: "memory");                         \
        }                                                                            \
        __builtin_amdgcn_s_barrier();                                                \
        ushort* tmpb = buf0; buf0 = buf1; buf1 = buf2; buf2 = tmpb;                  \
    }

// ---------------- GEMM1 split-K: part[kc] = h_chunk @ W_chunk^T ----------------
__global__ void __launch_bounds__(512, 2) gemm1_sk_kernel(
        const ushort* __restrict__ A,    // h bf16 [B][N]
        const ushort* __restrict__ Wb,   // [D][N] bf16
        float* __restrict__ part) {      // [SPLITK][B][D] f32
    __shared__ __attribute__((aligned(16))) ushort S[3 * 16384];  // 96 KB
    int n0 = blockIdx.x * 256, m0 = blockIdx.y * 256;
    int kb0 = blockIdx.z * KC;
    int t = threadIdx.x;
    int lane = t & 63, w = t >> 6;
    int wm = w >> 2, wn = w & 3;
    int quad = lane >> 4, lrow = lane & 15;
    int pchunk = (quad ^ ((lrow >> 1) & 3)) * 8 + lrow * 32;  // ushorts

    const ushort* gA = A + (size_t)m0 * Ndim + kb0;
    const ushort* gB = Wb + (size_t)n0 * Ndim + kb0;

    floatx4 acc[8][4];
    #pragma unroll
    for (int i = 0; i < 8; i++)
        #pragma unroll
        for (int j = 0; j < 4; j++) acc[i][j] = (floatx4)0.0f;

    GEMM_CORE_LOOP(64, gA, gB, Ndim)

    // epilogue: write f32 partials
    float* pb = &part[(size_t)blockIdx.z * Bdim * Ddim];
    #pragma unroll
    for (int fr = 0; fr < 8; fr++) {
        #pragma unroll
        for (int rr = 0; rr < 4; rr++) {
            int row = m0 + wm * 128 + fr * 16 + quad * 4 + rr;
            #pragma unroll
            for (int j = 0; j < 4; j++) {
                int col = n0 + wn * 64 + j * 16 + lrow;
                pb[(size_t)row * Ddim + col] = acc[fr][j][rr];
            }
        }
    }
}

// ---------------- GEMM2: recon loss partials ----------------
__global__ void __launch_bounds__(512, 2) gemm2_kernel(
        const ushort* __restrict__ enc,  // [B][D] bf16
        const ushort* __restrict__ Wt,   // [N][D] bf16
        const float* __restrict__ b2,
        const float* __restrict__ x,     // [B][N] f32
        float* __restrict__ num, float* __restrict__ den) {
    __shared__ __attribute__((aligned(16))) ushort S[3 * 16384];  // 96 KB
    int m0 = blockIdx.y * 256, n0 = blockIdx.x * 256;
    int t = threadIdx.x;
    int lane = t & 63, w = t >> 6;
    int wm = w >> 2, wn = w & 3;
    int quad = lane >> 4, lrow = lane & 15;
    int pchunk = (quad ^ ((lrow >> 1) & 3)) * 8 + lrow * 32;

    const ushort* gA = enc + (size_t)m0 * Ddim;
    const ushort* gB = Wt + (size_t)n0 * Ddim;

    floatx4 acc[8][4];
    #pragma unroll
    for (int i = 0; i < 8; i++)
        #pragma unroll
        for (int j = 0; j < 4; j++) acc[i][j] = (floatx4)0.0f;

    GEMM_CORE_LOOP(32, gA, gB, Ddim)

    // epilogue: per-row sum of (x - (acc+b2))^2 over this block's 256x256 tile.
    float b2v[4];
    #pragma unroll
    for (int j = 0; j < 4; j++) b2v[j] = b2[n0 + wn * 64 + j * 16 + lrow];

    #pragma unroll
    for (int fr = 0; fr < 8; fr++) {
        #pragma unroll
        for (int rr = 0; rr < 4; rr++) {
            int row = m0 + wm * 128 + fr * 16 + quad * 4 + rr;
            const float* xr = &x[(size_t)row * Ndim + n0];
            float ns = 0.0f, ds = 0.0f;
            #pragma unroll
            for (int j = 0; j < 4; j++) {
                int cl = wn * 64 + j * 16 + lrow;
                float recon = acc[fr][j][rr] + b2v[j];
                float xv = xr[cl];
                if (xv != 0.0f) {
                    float d = xv - recon;
                    ns += d * d;
                    ds += 1.0f;
                }
            }
            for (int s = 1; s < 16; s <<= 1) {
                ns += __shfl_xor(ns, s);
                ds += __shfl_xor(ds, s);
            }
            if (lrow == 0) {
                atomicAdd(&num[row], ns);
                atomicAdd(&den[row], ds);
            }
        }
    }
}

// ---------------- reduce partials + b1 + tanh -> enc; fused LayerNorm -> final ----------------
__global__ void reduce_ln_kernel(const float* __restrict__ part, const float* __restrict__ b1,
                                 const float* __restrict__ gamma, const float* __restrict__ beta,
                                 ushort* __restrict__ enc, float* __restrict__ out) {
    int row = blockIdx.x;
    int t = threadIdx.x;  // 256 threads, 4 elems each
    size_t base = (size_t)row * Ddim + t * 4;
    float4 v = *(const float4*)&part[base];
    #pragma unroll
    for (int kc = 1; kc < SPLITK; kc++) {
        float4 p = *(const float4*)&part[(size_t)kc * Bdim * Ddim + base];
        v.x += p.x; v.y += p.y; v.z += p.z; v.w += p.w;
    }
    float4 bb = *(const float4*)&b1[t * 4];
    float v0 = tanhf(v.x + bb.x), v1 = tanhf(v.y + bb.y);
    float v2 = tanhf(v.z + bb.z), v3 = tanhf(v.w + bb.w);
    uint2 eo;
    eo.x = pk(f2bf(v0), f2bf(v1));
    eo.y = pk(f2bf(v2), f2bf(v3));
    *(uint2*)&enc[base] = eo;
    float s = v0 + v1 + v2 + v3;
    float sq = v0 * v0 + v1 * v1 + v2 * v2 + v3 * v3;
    for (int sft = 1; sft < 64; sft <<= 1) {
        s += __shfl_xor(s, sft);
        sq += __shfl_xor(sq, sft);
    }
    __shared__ float red[8];
    int w = t >> 6, lane = t & 63;
    if (lane == 0) { red[w] = s; red[w + 4] = sq; }
    __syncthreads();
    s = red[0] + red[1] + red[2] + red[3];
    sq = red[4] + red[5] + red[6] + red[7];
    float mu = s * (1.0f / Ddim);
    float var = sq * (1.0f / Ddim) - mu * mu;
    float rstd = rsqrtf(var + 1e-5f);
    float4 g = *(const float4*)&gamma[t * 4];
    float4 b = *(const float4*)&beta[t * 4];
    float4 o;
    o.x = (v0 - mu) * rstd * g.x + b.x;
    o.y = (v1 - mu) * rstd * g.y + b.y;
    o.z = (v2 - mu) * rstd * g.z + b.z;
    o.w = (v3 - mu) * rstd * g.w + b.w;
    *(float4*)&out[base] = o;
}

// ---------------- GEMM1 fallback (no split-K ws): BM=128,BN=64,BK=64 ----------------
__global__ void __launch_bounds__(256) gemm1_kernel(
        const ushort* __restrict__ A, const ushort* __restrict__ Wb,
        const float* __restrict__ b1, ushort* __restrict__ enc) {
    const int K = Ndim;
    __shared__ __attribute__((aligned(16))) ushort As[128][64];
    __shared__ __attribute__((aligned(16))) ushort Bs[64][64];
    int m0 = blockIdx.y * 128, n0 = blockIdx.x * 64;
    int t = threadIdx.x;
    int lane = t & 63, w = t >> 6;
    int wm = w >> 1, wn = w & 1;
    int quad = lane >> 4, lrow = lane & 15;
    ushort* AsF = &As[0][0];
    ushort* BsF = &Bs[0][0];
    int wofs = (t & 192) * 8;

    floatx4 acc[4][2];
    for (int i = 0; i < 4; i++) for (int j = 0; j < 2; j++) acc[i][j] = (floatx4)0.0f;

    for (int k0 = 0; k0 < K; k0 += 64) {
        #pragma unroll
        for (int p = 0; p < 4; p++) {
            int c = p * 256 + t;
            int r = c >> 3, cc = c & 7;
            int g = cc ^ (r & 7);
            gl_lds16(&A[(size_t)(m0 + r) * K + k0 + g * 8], AsF + p * 2048 + wofs);
        }
        #pragma unroll
        for (int p = 0; p < 2; p++) {
            int c = p * 256 + t;
            int r = c >> 3, cc = c & 7;
            int g = cc ^ (r & 7);
            gl_lds16(&Wb[(size_t)(n0 + r) * K + k0 + g * 8], BsF + p * 2048 + wofs);
        }
        __syncthreads();
        short8 af[2][4], bfr[2][2];
        #pragma unroll
        for (int k1 = 0; k1 < 2; k1++) {
            #pragma unroll
            for (int i = 0; i < 4; i++) {
                int r = wm * 64 + i * 16 + lrow;
                int q = (k1 * 4 + quad) ^ (r & 7);
                af[k1][i] = *(const short8*)&As[r][q * 8];
            }
            #pragma unroll
            for (int j = 0; j < 2; j++) {
                int r = wn * 32 + j * 16 + lrow;
                int q = (k1 * 4 + quad) ^ (r & 7);
                bfr[k1][j] = *(const short8*)&Bs[r][q * 8];
            }
        }
        #pragma unroll
        for (int k1 = 0; k1 < 2; k1++)
            #pragma unroll
            for (int i = 0; i < 4; i++)
                #pragma unroll
                for (int j = 0; j < 2; j++)
                    acc[i][j] = __builtin_amdgcn_mfma_f32_16x16x32_bf16(af[k1][i], bfr[k1][j], acc[i][j], 0, 0, 0);
        __syncthreads();
    }
    for (int j = 0; j < 2; j++) {
        int col = n0 + wn * 32 + j * 16 + lrow;
        float bb = b1[col];
        for (int i = 0; i < 4; i++) {
            for (int r = 0; r < 4; r++) {
                int row = m0 + wm * 64 + i * 16 + quad * 4 + r;
                float v = tanhf(acc[i][j][r] + bb);
                enc[(size_t)row * Ddim + col] = f2bf(v);
            }
        }
    }
}

// ---------------- GEMM1 fallback (ws too small): convert x*mask in-staging ----------------
__global__ void gemm1_conv_kernel(const float* __restrict__ x, const float* __restrict__ mask,
                                  const ushort* __restrict__ Wb, const float* __restrict__ b1,
                                  ushort* __restrict__ enc) {
    const int K = Ndim;
    __shared__ __attribute__((aligned(16))) ushort As[128][32];
    __shared__ __attribute__((aligned(16))) ushort Bs[64][32];
    int m0 = blockIdx.y * 128, n0 = blockIdx.x * 64;
    int t = threadIdx.x;
    int lane = t & 63, w = t >> 6;
    int wm = w >> 1, wn = w & 1;
    int quad = lane >> 4, lrow = lane & 15;
    const float C = 1.0f / 0.75f;

    floatx4 acc[4][2];
    for (int i = 0; i < 4; i++) for (int j = 0; j < 2; j++) acc[i][j] = (floatx4)0.0f;

    for (int k0 = 0; k0 < K; k0 += 32) {
        for (int c = t; c < 512; c += 256) {
            int r = c >> 2, cc = (c & 3) * 8;
            const float* px = &x[(size_t)(m0 + r) * K + k0 + cc];
            const float* pm = &mask[(size_t)(m0 + r) * K + k0 + cc];
            float4 xa = *(const float4*)px, xb = *(const float4*)(px + 4);
            float4 ma = *(const float4*)pm, mb = *(const float4*)(pm + 4);
            uint4 o;
            o.x = pk(f2bf(xa.x * ma.x * C), f2bf(xa.y * ma.y * C));
            o.y = pk(f2bf(xa.z * ma.z * C), f2bf(xa.w * ma.w * C));
            o.z = pk(f2bf(xb.x * mb.x * C), f2bf(xb.y * mb.y * C));
            o.w = pk(f2bf(xb.z * mb.z * C), f2bf(xb.w * mb.w * C));
            *(uint4*)&As[r][cc] = o;
        }
        {
            int c = t;
            int r = c >> 2, cc = (c & 3) * 8;
            *(uint4*)&Bs[r][cc] = *(const uint4*)&Wb[(size_t)(n0 + r) * K + k0 + cc];
        }
        __syncthreads();
        short8 af[4], bfr[2];
        for (int i = 0; i < 4; i++) af[i] = *(const short8*)&As[wm * 64 + i * 16 + lrow][quad * 8];
        for (int j = 0; j < 2; j++) bfr[j] = *(const short8*)&Bs[wn * 32 + j * 16 + lrow][quad * 8];
        for (int i = 0; i < 4; i++)
            for (int j = 0; j < 2; j++)
                acc[i][j] = __builtin_amdgcn_mfma_f32_16x16x32_bf16(af[i], bfr[j], acc[i][j], 0, 0, 0);
        __syncthreads();
    }
    for (int j = 0; j < 2; j++) {
        int col = n0 + wn * 32 + j * 16 + lrow;
        float bb = b1[col];
        for (int i = 0; i < 4; i++) {
            for (int r = 0; r < 4; r++) {
                int row = m0 + wm * 64 + i * 16 + quad * 4 + r;
                float v = tanhf(acc[i][j][r] + bb);
                enc[(size_t)row * Ddim + col] = f2bf(v);
            }
        }
    }
}

// ---------------- LayerNorm over D (fallback path) ----------------
__global__ void ln_kernel(const ushort* __restrict__ enc, const float* __restrict__ gamma,
                          const float* __restrict__ beta, float* __restrict__ out) {
    int row = blockIdx.x;
    int t = threadIdx.x;
    const ushort* e = &enc[(size_t)row * Ddim];
    uint2 u = *(const uint2*)&e[t * 4];
    float v0 = bf2f((ushort)(u.x & 0xFFFF)), v1 = bf2f((ushort)(u.x >> 16));
    float v2 = bf2f((ushort)(u.y & 0xFFFF)), v3 = bf2f((ushort)(u.y >> 16));
    float s = v0 + v1 + v2 + v3;
    float sq = v0 * v0 + v1 * v1 + v2 * v2 + v3 * v3;
    for (int sft = 1; sft < 64; sft <<= 1) {
        s += __shfl_xor(s, sft);
        sq += __shfl_xor(sq, sft);
    }
    __shared__ float red[8];
    int w = t >> 6, lane = t & 63;
    if (lane == 0) { red[w] = s; red[w + 4] = sq; }
    __syncthreads();
    s = red[0] + red[1] + red[2] + red[3];
    sq = red[4] + red[5] + red[6] + red[7];
    float mu = s * (1.0f / Ddim);
    float var = sq * (1.0f / Ddim) - mu * mu;
    float rstd = rsqrtf(var + 1e-5f);
    float4 g = *(const float4*)&gamma[t * 4];
    float4 b = *(const float4*)&beta[t * 4];
    float4 o;
    o.x = (v0 - mu) * rstd * g.x + b.x;
    o.y = (v1 - mu) * rstd * g.y + b.y;
    o.z = (v2 - mu) * rstd * g.z + b.z;
    o.w = (v3 - mu) * rstd * g.w + b.w;
    *(float4*)&out[(size_t)row * Ddim + t * 4] = o;
}

// ---------------- loss = sum_b num[b]/den[b] ----------------
__global__ void loss_final_kernel(const float* __restrict__ num, const float* __restrict__ den,
                                  float* __restrict__ out) {
    int t = threadIdx.x;
    float s = 0.0f;
    for (int i = t; i < Bdim; i += 256) s += num[i] / den[i];
    for (int sft = 1; sft < 64; sft <<= 1) s += __shfl_xor(s, sft);
    __shared__ float red[4];
    int w = t >> 6, lane = t & 63;
    if (lane == 0) red[w] = s;
    __syncthreads();
    if (t == 0) out[0] = red[0] + red[1] + red[2] + red[3];
}

// ---------------- workspace layout ----------------
#define WB_OFF   0ull
#define WB_SZ    ((size_t)Ddim * Ndim * 2)            // 16 MiB
#define WT_OFF   (WB_OFF + WB_SZ)
#define WT_SZ    ((size_t)Ndim * Ddim * 2)            // 16 MiB
#define ENC_OFF  (WT_OFF + WT_SZ)
#define ENC_SZ   ((size_t)Bdim * Ddim * 2)            // 8 MiB
#define NUM_OFF  (ENC_OFF + ENC_SZ)
#define NUM_SZ   ((size_t)Bdim * 4)
#define DEN_OFF  (NUM_OFF + NUM_SZ)
#define DEN_SZ   ((size_t)Bdim * 4)
#define H_OFF    (DEN_OFF + DEN_SZ)
#define H_SZ     ((size_t)Bdim * Ndim * 2)            // 64 MiB
#define FAST_NEED (H_OFF + H_SZ)
#define PART_OFF FAST_NEED
#define PART_SZ  ((size_t)SPLITK * Bdim * Ddim * 4)   // 64 MiB
#define SPLIT_NEED (PART_OFF + PART_SZ)

extern "C" void kernel_launch(void* const* d_in, const int* in_sizes, int n_in,
                              void* d_out, int out_size, void* d_ws, size_t ws_size,
                              hipStream_t stream) {
    const float* x     = (const float*)d_in[0];
    const float* mask  = (const float*)d_in[1];
    const float* W     = (const float*)d_in[2];
    const float* b1    = (const float*)d_in[3];
    const float* b2    = (const float*)d_in[4];
    const float* gamma = (const float*)d_in[5];
    const float* beta  = (const float*)d_in[6];

    float* final_out = (float*)d_out;                       // [B*D]
    float* loss_out  = final_out + (size_t)Bdim * Ddim;     // [1]

    char* ws = (char*)d_ws;
    ushort* Wb   = (ushort*)(ws + WB_OFF);
    ushort* Wt   = (ushort*)(ws + WT_OFF);
    ushort* enc  = (ushort*)(ws + ENC_OFF);
    float*  num  = (float*)(ws + NUM_OFF);
    float*  den  = (float*)(ws + DEN_OFF);
    ushort* hbuf = (ushort*)(ws + H_OFF);
    float*  part = (float*)(ws + PART_OFF);

    hipMemsetAsync(num, 0, NUM_SZ + DEN_SZ, stream);

    prep_w_kernel<<<dim3(Ndim / 64, Ddim / 64), dim3(64, 4), 0, stream>>>(W, Wb, Wt);

    if (ws_size >= SPLIT_NEED) {
        prep_h_kernel<<<(Bdim * (size_t)Ndim) / 8 / 256, 256, 0, stream>>>(x, mask, hbuf);
        gemm1_sk_kernel<<<dim3(Ddim / 256, Bdim / 256, SPLITK), 512, 0, stream>>>(hbuf, Wb, part);
        reduce_ln_kernel<<<Bdim, 256, 0, stream>>>(part, b1, gamma, beta, enc, final_out);
    } else if (ws_size >= FAST_NEED) {
        prep_h_kernel<<<(Bdim * (size_t)Ndim) / 8 / 256, 256, 0, stream>>>(x, mask, hbuf);
        gemm1_kernel<<<dim3(Ddim / 64, Bdim / 128), 256, 0, stream>>>(hbuf, Wb, b1, enc);
        ln_kernel<<<Bdim, 256, 0, stream>>>(enc, gamma, beta, final_out);
    } else {
        gemm1_conv_kernel<<<dim3(Ddim / 64, Bdim / 128), 256, 0, stream>>>(x, mask, Wb, b1, enc);
        ln_kernel<<<Bdim, 256, 0, stream>>>(enc, gamma, beta, final_out);
    }

    gemm2_kernel<<<dim3(Ndim / 256, Bdim / 256), 512, 0, stream>>>(enc, Wt, b2, x, num, den);

    loss_final_kernel<<<1, 256, 0, stream>>>(num, den, loss_out);
}

// Round 3
// 524.393 us; speedup vs baseline: 1.1925x; 1.0331x over previous
//
#include <hip/hip_runtime.h>
#include <hip/hip_bf16.h>

// Problem: B=4096, N=8192, D=1024
//   h = x*mask/0.75
//   enc = tanh(h @ W^T + b1)          GEMM1: [B,N]x[D,N]^T -> [B,D]  (split-K=4)
//   final = LN_D(enc)*gamma + beta    (output 0, B*D f32)
//   recon = enc @ W + b2              GEMM2: [B,D]x[D,N] -> [B,N] (not materialized)
//   loss = sum_b sum_n (nz*(x-recon))^2 / sum_n nz    (output 1, 1 f32)
//
// R3: m201-geometry GEMM core: 256x256 tile, BK=64, 8 waves (2Mx4N, wave tile
//     128x64), 2-dbuf 128 KiB LDS. 4 quadrant-phases per K-tile (16 MFMA each,
//     frag carryover: 12/4/8/0 ds_reads). Quadrant-shaped staging halves with
//     derived per-phase counted waits: vmcnt(6),vmcnt(6),-,vmcnt(4) — never
//     drains below 4 in the main loop. One barrier/phase, lgkm drain before
//     barrier (write-safety), sched_barrier+setprio around MFMA clusters.
//     Bijective XCD swizzle on both GEMM grids.

#define Bdim 4096
#define Ndim 8192
#define Ddim 1024
#define SPLITK 4
#define KC (Ndim / SPLITK)   // 2048

typedef short short8 __attribute__((ext_vector_type(8)));
typedef float floatx4 __attribute__((ext_vector_type(4)));

__device__ __forceinline__ ushort f2bf(float f) {
    union { float f; unsigned int u; } v; v.f = f;
    unsigned int r = (v.u + 0x7FFFu + ((v.u >> 16) & 1u)) >> 16;
    return (ushort)r;
}
__device__ __forceinline__ float bf2f(ushort u) {
    union { unsigned int u; float f; } v; v.u = ((unsigned int)u) << 16;
    return v.f;
}
__device__ __forceinline__ unsigned int pk(ushort a, ushort b) {
    return (unsigned int)a | ((unsigned int)b << 16);
}

// async global->LDS, 16B per lane. LDS dest is wave-uniform base + lane*16.
__device__ __forceinline__ void gl_lds16(const void* g, void* l) {
    __builtin_amdgcn_global_load_lds(
        (const __attribute__((address_space(1))) unsigned int*)g,
        (__attribute__((address_space(3))) unsigned int*)l,
        16, 0, 0);
}

// ---------------- prep: h = bf16(x*mask/0.75) ----------------
__global__ void prep_h_kernel(const float* __restrict__ x, const float* __restrict__ mask,
                              ushort* __restrict__ h) {
    const float C = 1.0f / 0.75f;
    size_t i = ((size_t)blockIdx.x * 256 + threadIdx.x) * 8;
    float4 x0 = *(const float4*)&x[i];
    float4 x1 = *(const float4*)&x[i + 4];
    float4 m0 = *(const float4*)&mask[i];
    float4 m1 = *(const float4*)&mask[i + 4];
    uint4 o;
    o.x = pk(f2bf(x0.x * m0.x * C), f2bf(x0.y * m0.y * C));
    o.y = pk(f2bf(x0.z * m0.z * C), f2bf(x0.w * m0.w * C));
    o.z = pk(f2bf(x1.x * m1.x * C), f2bf(x1.y * m1.y * C));
    o.w = pk(f2bf(x1.z * m1.z * C), f2bf(x1.w * m1.w * C));
    *(uint4*)&h[i] = o;
}

// ---------------- prep: Wb = bf16(W), Wt = bf16(W^T) ----------------
__global__ void prep_w_kernel(const float* __restrict__ W, ushort* __restrict__ Wb,
                              ushort* __restrict__ Wt) {
    __shared__ float tl[64][65];
    int n0 = blockIdx.x * 64, d0 = blockIdx.y * 64;
    int tx = threadIdx.x, ty = threadIdx.y;  // 64 x 4
    for (int i = ty; i < 64; i += 4) {
        float v = W[(size_t)(d0 + i) * Ndim + n0 + tx];
        tl[i][tx] = v;
        Wb[(size_t)(d0 + i) * Ndim + n0 + tx] = f2bf(v);
    }
    __syncthreads();
    for (int i = ty; i < 64; i += 4)
        Wt[(size_t)(n0 + i) * Ddim + d0 + tx] = f2bf(tl[tx][i]);
}

// ======================= 256x256 BK=64 8-phase GEMM core =======================
// LDS: S[65536] ushorts = 128 KB. dbuf d at d*32768: A 256x64 at +0 (16384),
// B 256x64 at +16384. Row r at r*64 ushorts; chunk c (8 bf16) XOR-swizzled:
// LDS[r][c] holds global chunk c ^ (r&7). Stage source applies gc=(l&7)^(l>>3).
//
// Reads (per wave, lane = quad*16+lrow):
//   A frag (fr,kc): row wm*128+fr*16+lrow, phys chunk (kc*4+quad)^(lrow&7)
//   B frag (fr,kc): row wn*64 +fr*16+lrow, same swizzle
// Quadrant phases per K-tile: P1=(mh0,nh0) reads A0(8)+B0(4); P2=(mh0,nh1)
// reads B1(4); P3=(mh1,nh1) reads A1(8); P4=(mh1,nh0) reads 0.
// Staging halves (16 KB = 2 gl_lds16/thread each), deadlines:
//   HA(q): A rows {q*64+[0,64)} u {128+q*64+[0,64)}     -> needed P(q?3:1)
//   HB(q): B rows {64k + q*32 + [0,32), k=0..3}         -> needed P(q?2:1)
// During tile u: P1 stages HA0,HB0(u+1); P2 stages HB1(u+1); P3 stages HA1(u+1).
// Waits (derived): P1-end vmcnt(6); P2-end vmcnt(6); P3-end none; P4-end vmcnt(4).

#define READS_A(arr, MH, D_)                                                          \
    _Pragma("unroll")                                                                 \
    for (int i_ = 0; i_ < 4; i_++) {                                                  \
        arr[i_][0] = *(const short8*)(Sa + (D_)*32768 + (MH)*4096 + i_*1024 + sw0);   \
        arr[i_][1] = *(const short8*)(Sa + (D_)*32768 + (MH)*4096 + i_*1024 + sw1);   \
    }
#define READS_B(arr, NH, D_)                                                          \
    _Pragma("unroll")                                                                 \
    for (int j_ = 0; j_ < 2; j_++) {                                                  \
        arr[j_][0] = *(const short8*)(Sb + (D_)*32768 + (NH)*2048 + j_*1024 + sw0);   \
        arr[j_][1] = *(const short8*)(Sb + (D_)*32768 + (NH)*2048 + j_*1024 + sw1);   \
    }
#define MFMA16(MH, NH, A_, B_)                                                        \
    _Pragma("unroll")                                                                 \
    for (int kc_ = 0; kc_ < 2; kc_++)                                                 \
        _Pragma("unroll")                                                             \
        for (int i_ = 0; i_ < 4; i_++)                                                \
            _Pragma("unroll")                                                         \
            for (int j_ = 0; j_ < 2; j_++)                                            \
                acc[(MH)*4 + i_][(NH)*2 + j_] = __builtin_amdgcn_mfma_f32_16x16x32_bf16( \
                    A_[i_][kc_], B_[j_][kc_], acc[(MH)*4 + i_][(NH)*2 + j_], 0, 0, 0);

#define STG_A(Q_, KT_, D_) {                                                          \
    gl_lds16(gAr + (size_t)((Q_)*64) * ldg + (size_t)(KT_)*64,                        \
             SdA + (D_)*32768 + ((Q_)*64)*64);                                        \
    gl_lds16(gAr + (size_t)((Q_)*64 + 128) * ldg + (size_t)(KT_)*64,                  \
             SdA + (D_)*32768 + ((Q_)*64 + 128)*64); }
#define STG_B(Q_, KT_, D_) {                                                          \
    gl_lds16(gBr + (size_t)((Q_)*32) * ldg + (size_t)(KT_)*64,                        \
             SdB + (D_)*32768 + ((Q_)*32)*64);                                        \
    gl_lds16(gBr + (size_t)((Q_)*32 + 128) * ldg + (size_t)(KT_)*64,                  \
             SdB + (D_)*32768 + ((Q_)*32 + 128)*64); }

#define PH_TAIL(PRIO_BODY)                                                            \
    __builtin_amdgcn_s_barrier();                                                     \
    __builtin_amdgcn_sched_barrier(0);                                                \
    __builtin_amdgcn_s_setprio(1);                                                    \
    PRIO_BODY                                                                         \
    __builtin_amdgcn_s_setprio(0);

// One K-tile in dbuf D_, staging tile UKT_ into dbuf D_^1 when ST_ is 1.
#define KTILE(D_, UKT_, ST_) {                                                        \
    short8 a0f[4][2], a1f[4][2], b0f[2][2], b1f[2][2];                                \
    /* P1: Q(mh0,nh0) */                                                              \
    READS_A(a0f, 0, D_); READS_B(b0f, 0, D_);                                         \
    if (ST_) { STG_A(0, UKT_, (D_)^1); STG_B(0, UKT_, (D_)^1); }                      \
    asm volatile("s_waitcnt lgkmcnt(0)" ::: "memory");                                \
    if (ST_) { asm volatile("s_waitcnt vmcnt(6)" ::: "memory"); }                     \
    else     { asm volatile("s_waitcnt vmcnt(2)" ::: "memory"); }                     \
    PH_TAIL(MFMA16(0, 0, a0f, b0f))                                                   \
    /* P2: Q(mh0,nh1) */                                                              \
    READS_B(b1f, 1, D_);                                                              \
    if (ST_) STG_B(1, UKT_, (D_)^1);                                                  \
    asm volatile("s_waitcnt lgkmcnt(0)" ::: "memory");                                \
    if (ST_) { asm volatile("s_waitcnt vmcnt(6)" ::: "memory"); }                     \
    else     { asm volatile("s_waitcnt vmcnt(0)" ::: "memory"); }                     \
    PH_TAIL(MFMA16(0, 1, a0f, b1f))                                                   \
    /* P3: Q(mh1,nh1) */                                                              \
    READS_A(a1f, 1, D_);                                                              \
    if (ST_) STG_A(1, UKT_, (D_)^1);                                                  \
    asm volatile("s_waitcnt lgkmcnt(0)" ::: "memory");                                \
    PH_TAIL(MFMA16(1, 1, a1f, b1f))                                                   \
    /* P4: Q(mh1,nh0), no reads/stages */                                             \
    asm volatile("s_waitcnt vmcnt(4)" ::: "memory");                                  \
    PH_TAIL(MFMA16(1, 0, a1f, b0f))                                                   \
}

// Shared per-kernel setup for the core (expects: S, t, and gA/gB/ldg pointers).
#define CORE_SETUP(LDG_)                                                              \
    const long ldg = (LDG_);                                                          \
    int t = threadIdx.x;                                                              \
    int lane = t & 63, w = t >> 6, l = lane;                                          \
    int wm = w >> 2, wn = w & 3;                                                      \
    int quad = lane >> 4, lrow = lane & 15;                                           \
    int gc = (l & 7) ^ (l >> 3);                                                      \
    const ushort* Sa = S + (wm * 128 + lrow) * 64;                                    \
    const ushort* Sb = S + 16384 + (wn * 64 + lrow) * 64;                             \
    int sw0 = ((quad) ^ (lrow & 7)) * 8;                                              \
    int sw1 = ((4 + quad) ^ (lrow & 7)) * 8;                                          \
    const ushort* gAr = gA + (size_t)(w * 8 + (l >> 3)) * ldg + gc * 8;               \
    const ushort* gBr = gB + (size_t)((w >> 2) * 64 + (w & 3) * 8 + (l >> 3)) * ldg + gc * 8; \
    ushort* SdA = S + (w * 8) * 64;                                                   \
    ushort* SdB = S + 16384 + ((w >> 2) * 64 + (w & 3) * 8) * 64;                     \
    floatx4 acc[8][4];                                                                \
    _Pragma("unroll")                                                                 \
    for (int i_ = 0; i_ < 8; i_++)                                                    \
        _Pragma("unroll")                                                             \
        for (int j_ = 0; j_ < 4; j_++) acc[i_][j_] = (floatx4)0.0f;

#define CORE_RUN(NKT_)                                                                \
    STG_A(0, 0, 0); STG_B(0, 0, 0); STG_B(1, 0, 0); STG_A(1, 0, 0);                   \
    asm volatile("s_waitcnt vmcnt(4)" ::: "memory");                                  \
    __builtin_amdgcn_s_barrier();                                                     \
    _Pragma("unroll 1")                                                               \
    for (int i = 0; i < (NKT_)/2 - 1; i++) {                                          \
        KTILE(0, 2*i + 1, 1)                                                          \
        KTILE(1, 2*i + 2, 1)                                                          \
    }                                                                                 \
    KTILE(0, (NKT_)-1, 1)                                                             \
    KTILE(1, 0, 0)

// ---------------- GEMM1 split-K: part[kc] = h_chunk @ W_chunk^T ----------------
__global__ void __launch_bounds__(512, 2) gemm1_sk_kernel(
        const ushort* __restrict__ A,    // h bf16 [B][N]
        const ushort* __restrict__ Wb,   // [D][N] bf16
        float* __restrict__ part) {      // [SPLITK][B][D] f32
    __shared__ __attribute__((aligned(16))) ushort S[65536];  // 128 KB
    // bijective XCD swizzle over 256 wgs (grid 4 x 16 x 4)
    int flat = (blockIdx.z * 16 + blockIdx.y) * 4 + blockIdx.x;
    int swz = (flat & 7) * 32 + (flat >> 3);
    int bx = swz & 3, by = (swz >> 2) & 15, bz = swz >> 6;
    int n0 = bx * 256, m0 = by * 256;
    int kb0 = bz * KC;

    const ushort* gA = A + (size_t)m0 * Ndim + kb0;
    const ushort* gB = Wb + (size_t)n0 * Ndim + kb0;

    CORE_SETUP(Ndim)
    CORE_RUN(KC / 64)   // 32 K-tiles

    // epilogue: write f32 partials
    float* pb = &part[(size_t)bz * Bdim * Ddim];
    #pragma unroll
    for (int fr = 0; fr < 8; fr++) {
        #pragma unroll
        for (int rr = 0; rr < 4; rr++) {
            int row = m0 + wm * 128 + fr * 16 + quad * 4 + rr;
            #pragma unroll
            for (int j = 0; j < 4; j++) {
                int col = n0 + wn * 64 + j * 16 + lrow;
                pb[(size_t)row * Ddim + col] = acc[fr][j][rr];
            }
        }
    }
}

// ---------------- GEMM2: recon loss partials ----------------
__global__ void __launch_bounds__(512, 2) gemm2_kernel(
        const ushort* __restrict__ enc,  // [B][D] bf16
        const ushort* __restrict__ Wt,   // [N][D] bf16
        const float* __restrict__ b2,
        const float* __restrict__ x,     // [B][N] f32
        float* __restrict__ num, float* __restrict__ den) {
    __shared__ __attribute__((aligned(16))) ushort S[65536];  // 128 KB
    // bijective XCD swizzle over 512 wgs (grid 32 x 16)
    int flat = blockIdx.y * 32 + blockIdx.x;
    int swz = (flat & 7) * 64 + (flat >> 3);
    int bx = swz & 31, by = swz >> 5;
    int n0 = bx * 256, m0 = by * 256;

    const ushort* gA = enc + (size_t)m0 * Ddim;
    const ushort* gB = Wt + (size_t)n0 * Ddim;

    CORE_SETUP(Ddim)
    CORE_RUN(Ddim / 64)   // 16 K-tiles

    // epilogue: per-row sum of (x - (acc+b2))^2 over this block's 256x256 tile.
    float b2v[4];
    #pragma unroll
    for (int j = 0; j < 4; j++) b2v[j] = b2[n0 + wn * 64 + j * 16 + lrow];

    #pragma unroll
    for (int fr = 0; fr < 8; fr++) {
        #pragma unroll
        for (int rr = 0; rr < 4; rr++) {
            int row = m0 + wm * 128 + fr * 16 + quad * 4 + rr;
            const float* xr = &x[(size_t)row * Ndim + n0];
            float ns = 0.0f, ds = 0.0f;
            #pragma unroll
            for (int j = 0; j < 4; j++) {
                int cl = wn * 64 + j * 16 + lrow;
                float recon = acc[fr][j][rr] + b2v[j];
                float xv = xr[cl];
                if (xv != 0.0f) {
                    float d = xv - recon;
                    ns += d * d;
                    ds += 1.0f;
                }
            }
            for (int s = 1; s < 16; s <<= 1) {
                ns += __shfl_xor(ns, s);
                ds += __shfl_xor(ds, s);
            }
            if (lrow == 0) {
                atomicAdd(&num[row], ns);
                atomicAdd(&den[row], ds);
            }
        }
    }
}

// ---------------- reduce partials + b1 + tanh -> enc; fused LayerNorm -> final ----------------
__global__ void reduce_ln_kernel(const float* __restrict__ part, const float* __restrict__ b1,
                                 const float* __restrict__ gamma, const float* __restrict__ beta,
                                 ushort* __restrict__ enc, float* __restrict__ out) {
    int row = blockIdx.x;
    int t = threadIdx.x;  // 256 threads, 4 elems each
    size_t base = (size_t)row * Ddim + t * 4;
    float4 v = *(const float4*)&part[base];
    #pragma unroll
    for (int kc = 1; kc < SPLITK; kc++) {
        float4 p = *(const float4*)&part[(size_t)kc * Bdim * Ddim + base];
        v.x += p.x; v.y += p.y; v.z += p.z; v.w += p.w;
    }
    float4 bb = *(const float4*)&b1[t * 4];
    float v0 = tanhf(v.x + bb.x), v1 = tanhf(v.y + bb.y);
    float v2 = tanhf(v.z + bb.z), v3 = tanhf(v.w + bb.w);
    uint2 eo;
    eo.x = pk(f2bf(v0), f2bf(v1));
    eo.y = pk(f2bf(v2), f2bf(v3));
    *(uint2*)&enc[base] = eo;
    float s = v0 + v1 + v2 + v3;
    float sq = v0 * v0 + v1 * v1 + v2 * v2 + v3 * v3;
    for (int sft = 1; sft < 64; sft <<= 1) {
        s += __shfl_xor(s, sft);
        sq += __shfl_xor(sq, sft);
    }
    __shared__ float red[8];
    int w = t >> 6, lane = t & 63;
    if (lane == 0) { red[w] = s; red[w + 4] = sq; }
    __syncthreads();
    s = red[0] + red[1] + red[2] + red[3];
    sq = red[4] + red[5] + red[6] + red[7];
    float mu = s * (1.0f / Ddim);
    float var = sq * (1.0f / Ddim) - mu * mu;
    float rstd = rsqrtf(var + 1e-5f);
    float4 g = *(const float4*)&gamma[t * 4];
    float4 b = *(const float4*)&beta[t * 4];
    float4 o;
    o.x = (v0 - mu) * rstd * g.x + b.x;
    o.y = (v1 - mu) * rstd * g.y + b.y;
    o.z = (v2 - mu) * rstd * g.z + b.z;
    o.w = (v3 - mu) * rstd * g.w + b.w;
    *(float4*)&out[base] = o;
}

// ---------------- GEMM1 fallback (no split-K ws): BM=128,BN=64,BK=64 ----------------
__global__ void __launch_bounds__(256) gemm1_kernel(
        const ushort* __restrict__ A, const ushort* __restrict__ Wb,
        const float* __restrict__ b1, ushort* __restrict__ enc) {
    const int K = Ndim;
    __shared__ __attribute__((aligned(16))) ushort As[128][64];
    __shared__ __attribute__((aligned(16))) ushort Bs[64][64];
    int m0 = blockIdx.y * 128, n0 = blockIdx.x * 64;
    int t = threadIdx.x;
    int lane = t & 63, w = t >> 6;
    int wm = w >> 1, wn = w & 1;
    int quad = lane >> 4, lrow = lane & 15;
    ushort* AsF = &As[0][0];
    ushort* BsF = &Bs[0][0];
    int wofs = (t & 192) * 8;

    floatx4 acc[4][2];
    for (int i = 0; i < 4; i++) for (int j = 0; j < 2; j++) acc[i][j] = (floatx4)0.0f;

    for (int k0 = 0; k0 < K; k0 += 64) {
        #pragma unroll
        for (int p = 0; p < 4; p++) {
            int c = p * 256 + t;
            int r = c >> 3, cc = c & 7;
            int g = cc ^ (r & 7);
            gl_lds16(&A[(size_t)(m0 + r) * K + k0 + g * 8], AsF + p * 2048 + wofs);
        }
        #pragma unroll
        for (int p = 0; p < 2; p++) {
            int c = p * 256 + t;
            int r = c >> 3, cc = c & 7;
            int g = cc ^ (r & 7);
            gl_lds16(&Wb[(size_t)(n0 + r) * K + k0 + g * 8], BsF + p * 2048 + wofs);
        }
        __syncthreads();
        short8 af[2][4], bfr[2][2];
        #pragma unroll
        for (int k1 = 0; k1 < 2; k1++) {
            #pragma unroll
            for (int i = 0; i < 4; i++) {
                int r = wm * 64 + i * 16 + lrow;
                int q = (k1 * 4 + quad) ^ (r & 7);
                af[k1][i] = *(const short8*)&As[r][q * 8];
            }
            #pragma unroll
            for (int j = 0; j < 2; j++) {
                int r = wn * 32 + j * 16 + lrow;
                int q = (k1 * 4 + quad) ^ (r & 7);
                bfr[k1][j] = *(const short8*)&Bs[r][q * 8];
            }
        }
        #pragma unroll
        for (int k1 = 0; k1 < 2; k1++)
            #pragma unroll
            for (int i = 0; i < 4; i++)
                #pragma unroll
                for (int j = 0; j < 2; j++)
                    acc[i][j] = __builtin_amdgcn_mfma_f32_16x16x32_bf16(af[k1][i], bfr[k1][j], acc[i][j], 0, 0, 0);
        __syncthreads();
    }
    for (int j = 0; j < 2; j++) {
        int col = n0 + wn * 32 + j * 16 + lrow;
        float bb = b1[col];
        for (int i = 0; i < 4; i++) {
            for (int r = 0; r < 4; r++) {
                int row = m0 + wm * 64 + i * 16 + quad * 4 + r;
                float v = tanhf(acc[i][j][r] + bb);
                enc[(size_t)row * Ddim + col] = f2bf(v);
            }
        }
    }
}

// ---------------- GEMM1 fallback (ws too small): convert x*mask in-staging ----------------
__global__ void gemm1_conv_kernel(const float* __restrict__ x, const float* __restrict__ mask,
                                  const ushort* __restrict__ Wb, const float* __restrict__ b1,
                                  ushort* __restrict__ enc) {
    const int K = Ndim;
    __shared__ __attribute__((aligned(16))) ushort As[128][32];
    __shared__ __attribute__((aligned(16))) ushort Bs[64][32];
    int m0 = blockIdx.y * 128, n0 = blockIdx.x * 64;
    int t = threadIdx.x;
    int lane = t & 63, w = t >> 6;
    int wm = w >> 1, wn = w & 1;
    int quad = lane >> 4, lrow = lane & 15;
    const float C = 1.0f / 0.75f;

    floatx4 acc[4][2];
    for (int i = 0; i < 4; i++) for (int j = 0; j < 2; j++) acc[i][j] = (floatx4)0.0f;

    for (int k0 = 0; k0 < K; k0 += 32) {
        for (int c = t; c < 512; c += 256) {
            int r = c >> 2, cc = (c & 3) * 8;
            const float* px = &x[(size_t)(m0 + r) * K + k0 + cc];
            const float* pm = &mask[(size_t)(m0 + r) * K + k0 + cc];
            float4 xa = *(const float4*)px, xb = *(const float4*)(px + 4);
            float4 ma = *(const float4*)pm, mb = *(const float4*)(pm + 4);
            uint4 o;
            o.x = pk(f2bf(xa.x * ma.x * C), f2bf(xa.y * ma.y * C));
            o.y = pk(f2bf(xa.z * ma.z * C), f2bf(xa.w * ma.w * C));
            o.z = pk(f2bf(xb.x * mb.x * C), f2bf(xb.y * mb.y * C));
            o.w = pk(f2bf(xb.z * mb.z * C), f2bf(xb.w * mb.w * C));
            *(uint4*)&As[r][cc] = o;
        }
        {
            int c = t;
            int r = c >> 2, cc = (c & 3) * 8;
            *(uint4*)&Bs[r][cc] = *(const uint4*)&Wb[(size_t)(n0 + r) * K + k0 + cc];
        }
        __syncthreads();
        short8 af[4], bfr[2];
        for (int i = 0; i < 4; i++) af[i] = *(const short8*)&As[wm * 64 + i * 16 + lrow][quad * 8];
        for (int j = 0; j < 2; j++) bfr[j] = *(const short8*)&Bs[wn * 32 + j * 16 + lrow][quad * 8];
        for (int i = 0; i < 4; i++)
            for (int j = 0; j < 2; j++)
                acc[i][j] = __builtin_amdgcn_mfma_f32_16x16x32_bf16(af[i], bfr[j], acc[i][j], 0, 0, 0);
        __syncthreads();
    }
    for (int j = 0; j < 2; j++) {
        int col = n0 + wn * 32 + j * 16 + lrow;
        float bb = b1[col];
        for (int i = 0; i < 4; i++) {
            for (int r = 0; r < 4; r++) {
                int row = m0 + wm * 64 + i * 16 + quad * 4 + r;
                float v = tanhf(acc[i][j][r] + bb);
                enc[(size_t)row * Ddim + col] = f2bf(v);
            }
        }
    }
}

// ---------------- LayerNorm over D (fallback path) ----------------
__global__ void ln_kernel(const ushort* __restrict__ enc, const float* __restrict__ gamma,
                          const float* __restrict__ beta, float* __restrict__ out) {
    int row = blockIdx.x;
    int t = threadIdx.x;
    const ushort* e = &enc[(size_t)row * Ddim];
    uint2 u = *(const uint2*)&e[t * 4];
    float v0 = bf2f((ushort)(u.x & 0xFFFF)), v1 = bf2f((ushort)(u.x >> 16));
    float v2 = bf2f((ushort)(u.y & 0xFFFF)), v3 = bf2f((ushort)(u.y >> 16));
    float s = v0 + v1 + v2 + v3;
    float sq = v0 * v0 + v1 * v1 + v2 * v2 + v3 * v3;
    for (int sft = 1; sft < 64; sft <<= 1) {
        s += __shfl_xor(s, sft);
        sq += __shfl_xor(sq, sft);
    }
    __shared__ float red[8];
    int w = t >> 6, lane = t & 63;
    if (lane == 0) { red[w] = s; red[w + 4] = sq; }
    __syncthreads();
    s = red[0] + red[1] + red[2] + red[3];
    sq = red[4] + red[5] + red[6] + red[7];
    float mu = s * (1.0f / Ddim);
    float var = sq * (1.0f / Ddim) - mu * mu;
    float rstd = rsqrtf(var + 1e-5f);
    float4 g = *(const float4*)&gamma[t * 4];
    float4 b = *(const float4*)&beta[t * 4];
    float4 o;
    o.x = (v0 - mu) * rstd * g.x + b.x;
    o.y = (v1 - mu) * rstd * g.y + b.y;
    o.z = (v2 - mu) * rstd * g.z + b.z;
    o.w = (v3 - mu) * rstd * g.w + b.w;
    *(float4*)&out[(size_t)row * Ddim + t * 4] = o;
}

// ---------------- loss = sum_b num[b]/den[b] ----------------
__global__ void loss_final_kernel(const float* __restrict__ num, const float* __restrict__ den,
                                  float* __restrict__ out) {
    int t = threadIdx.x;
    float s = 0.0f;
    for (int i = t; i < Bdim; i += 256) s += num[i] / den[i];
    for (int sft = 1; sft < 64; sft <<= 1) s += __shfl_xor(s, sft);
    __shared__ float red[4];
    int w = t >> 6, lane = t & 63;
    if (lane == 0) red[w] = s;
    __syncthreads();
    if (t == 0) out[0] = red[0] + red[1] + red[2] + red[3];
}

// ---------------- workspace layout ----------------
#define WB_OFF   0ull
#define WB_SZ    ((size_t)Ddim * Ndim * 2)            // 16 MiB
#define WT_OFF   (WB_OFF + WB_SZ)
#define WT_SZ    ((size_t)Ndim * Ddim * 2)            // 16 MiB
#define ENC_OFF  (WT_OFF + WT_SZ)
#define ENC_SZ   ((size_t)Bdim * Ddim * 2)            // 8 MiB
#define NUM_OFF  (ENC_OFF + ENC_SZ)
#define NUM_SZ   ((size_t)Bdim * 4)
#define DEN_OFF  (NUM_OFF + NUM_SZ)
#define DEN_SZ   ((size_t)Bdim * 4)
#define H_OFF    (DEN_OFF + DEN_SZ)
#define H_SZ     ((size_t)Bdim * Ndim * 2)            // 64 MiB
#define FAST_NEED (H_OFF + H_SZ)
#define PART_OFF FAST_NEED
#define PART_SZ  ((size_t)SPLITK * Bdim * Ddim * 4)   // 64 MiB
#define SPLIT_NEED (PART_OFF + PART_SZ)

extern "C" void kernel_launch(void* const* d_in, const int* in_sizes, int n_in,
                              void* d_out, int out_size, void* d_ws, size_t ws_size,
                              hipStream_t stream) {
    const float* x     = (const float*)d_in[0];
    const float* mask  = (const float*)d_in[1];
    const float* W     = (const float*)d_in[2];
    const float* b1    = (const float*)d_in[3];
    const float* b2    = (const float*)d_in[4];
    const float* gamma = (const float*)d_in[5];
    const float* beta  = (const float*)d_in[6];

    float* final_out = (float*)d_out;                       // [B*D]
    float* loss_out  = final_out + (size_t)Bdim * Ddim;     // [1]

    char* ws = (char*)d_ws;
    ushort* Wb   = (ushort*)(ws + WB_OFF);
    ushort* Wt   = (ushort*)(ws + WT_OFF);
    ushort* enc  = (ushort*)(ws + ENC_OFF);
    float*  num  = (float*)(ws + NUM_OFF);
    float*  den  = (float*)(ws + DEN_OFF);
    ushort* hbuf = (ushort*)(ws + H_OFF);
    float*  part = (float*)(ws + PART_OFF);

    hipMemsetAsync(num, 0, NUM_SZ + DEN_SZ, stream);

    prep_w_kernel<<<dim3(Ndim / 64, Ddim / 64), dim3(64, 4), 0, stream>>>(W, Wb, Wt);

    if (ws_size >= SPLIT_NEED) {
        prep_h_kernel<<<(Bdim * (size_t)Ndim) / 8 / 256, 256, 0, stream>>>(x, mask, hbuf);
        gemm1_sk_kernel<<<dim3(Ddim / 256, Bdim / 256, SPLITK), 512, 0, stream>>>(hbuf, Wb, part);
        reduce_ln_kernel<<<Bdim, 256, 0, stream>>>(part, b1, gamma, beta, enc, final_out);
    } else if (ws_size >= FAST_NEED) {
        prep_h_kernel<<<(Bdim * (size_t)Ndim) / 8 / 256, 256, 0, stream>>>(x, mask, hbuf);
        gemm1_kernel<<<dim3(Ddim / 64, Bdim / 128), 256, 0, stream>>>(hbuf, Wb, b1, enc);
        ln_kernel<<<Bdim, 256, 0, stream>>>(enc, gamma, beta, final_out);
    } else {
        gemm1_conv_kernel<<<dim3(Ddim / 64, Bdim / 128), 256, 0, stream>>>(x, mask, Wb, b1, enc);
        ln_kernel<<<Bdim, 256, 0, stream>>>(enc, gamma, beta, final_out);
    }

    gemm2_kernel<<<dim3(Ndim / 256, Bdim / 256), 512, 0, stream>>>(enc, Wt, b2, x, num, den);

    loss_final_kernel<<<1, 256, 0, stream>>>(num, den, loss_out);
}